// Round 1
// baseline (84.657 us; speedup 1.0000x reference)
//
#include <hip/hip_runtime.h>

#define DIM 64

// Kernel 1: one 64-lane wave per node.
// s[i]   = dot(x[i], W_rel)
// out[i] = dot(x[i], W_root) + b_rel   (full overwrite -> replay-safe init)
__global__ void node_scores_kernel(const float* __restrict__ x,
                                   const float* __restrict__ W_rel,
                                   const float* __restrict__ b_rel,
                                   const float* __restrict__ W_root,
                                   float* __restrict__ s,
                                   float* __restrict__ out,
                                   int n) {
    int gtid = blockIdx.x * blockDim.x + threadIdx.x;
    int node = gtid >> 6;          // wave index = node
    int lane = threadIdx.x & 63;
    if (node >= n) return;

    float xv = x[(size_t)node * DIM + lane];
    float sr = xv * W_rel[lane];   // rel partial
    float st = xv * W_root[lane];  // root partial

    // 64-lane butterfly reduction
    #pragma unroll
    for (int off = 32; off > 0; off >>= 1) {
        sr += __shfl_xor(sr, off);
        st += __shfl_xor(st, off);
    }
    if (lane == 0) {
        s[node]   = sr;
        out[node] = st + b_rel[0];
    }
}

// Kernel 2: one thread per edge. Scalar scatter-add (s fits in L2).
__global__ void edge_scatter_kernel(const int* __restrict__ ei,
                                    const float* __restrict__ s,
                                    float* __restrict__ out,
                                    int E) {
    int e = blockIdx.x * blockDim.x + threadIdx.x;
    if (e >= E) return;
    int src = ei[e];        // row 0: source j
    int dst = ei[E + e];    // row 1: target i
    atomicAdd(&out[dst], s[src]);
}

extern "C" void kernel_launch(void* const* d_in, const int* in_sizes, int n_in,
                              void* d_out, int out_size, void* d_ws, size_t ws_size,
                              hipStream_t stream) {
    const float* x      = (const float*)d_in[0];
    const int*   ei     = (const int*)d_in[1];
    const float* W_rel  = (const float*)d_in[2];
    const float* b_rel  = (const float*)d_in[3];
    const float* W_root = (const float*)d_in[4];
    float* out = (float*)d_out;

    int n = out_size;                 // N_NODES (out is [N,1])
    int E = in_sizes[1] / 2;          // edge_index is [2, E]

    float* s = (float*)d_ws;          // n floats of scratch

    // Kernel 1: 4 nodes (waves) per 256-thread block
    int blocks1 = (n + 3) / 4;
    node_scores_kernel<<<blocks1, 256, 0, stream>>>(x, W_rel, b_rel, W_root, s, out, n);

    // Kernel 2: 1 thread per edge
    int blocks2 = (E + 255) / 256;
    edge_scatter_kernel<<<blocks2, 256, 0, stream>>>(ei, s, out, E);
}

// Round 2
// 81.551 us; speedup vs baseline: 1.0381x; 1.0381x over previous
//
#include <hip/hip_runtime.h>

#define DIM 64
#define NXCD 8

// Zero the 8 per-XCD partial copies (replay-safe: ws is not re-poisoned,
// so we must zero every call).
__global__ void zero_ws_kernel(float4* __restrict__ p, int n4) {
    int i = blockIdx.x * blockDim.x + threadIdx.x;
    if (i < n4) p[i] = make_float4(0.f, 0.f, 0.f, 0.f);
}

// 16 threads per node row, float4 loads (16B/lane).
// s[i]   = dot(x[i], W_rel)
// out[i] = dot(x[i], W_root) + b_rel   (full overwrite -> replay-safe)
__global__ void node_scores_kernel(const float4* __restrict__ x4,
                                   const float4* __restrict__ Wrel4,
                                   const float* __restrict__ b_rel,
                                   const float4* __restrict__ Wroot4,
                                   float* __restrict__ s,
                                   float* __restrict__ out,
                                   int n) {
    int tid = threadIdx.x;
    int node = blockIdx.x * 16 + (tid >> 4);   // 16 rows per 256-thread block
    int c = tid & 15;                           // float4 chunk within row
    if (node >= n) return;

    float4 xv = x4[(size_t)node * (DIM / 4) + c];
    float4 wr = Wrel4[c];
    float4 wt = Wroot4[c];
    float sr = xv.x * wr.x + xv.y * wr.y + xv.z * wr.z + xv.w * wr.w;
    float st = xv.x * wt.x + xv.y * wt.y + xv.z * wt.z + xv.w * wt.w;

    // reduce across the 16 lanes of this row
    #pragma unroll
    for (int off = 1; off < 16; off <<= 1) {
        sr += __shfl_xor(sr, off);
        st += __shfl_xor(st, off);
    }
    if (c == 0) {
        s[node]   = sr;
        out[node] = st + b_rel[0];
    }
}

// 8 edges per thread. Atomics go to this XCD's private copy with
// workgroup scope -> executed at the local TCC (L2), never forwarded
// to the memory-side atomic units. Copy k is only touched by XCD k.
__global__ void edge_scatter_kernel(const int* __restrict__ ei,
                                    const float* __restrict__ s,
                                    float* __restrict__ part,
                                    int E, int n) {
    unsigned xcc;
    asm volatile("s_getreg_b32 %0, hwreg(HW_REG_XCC_ID)" : "=s"(xcc));
    float* my = part + (size_t)(xcc & (NXCD - 1)) * n;

    int t = blockIdx.x * blockDim.x + threadIdx.x;
    int base = t * 8;
    if (base + 8 <= E) {
        const int4* sv = (const int4*)ei;
        const int4* dv = (const int4*)(ei + E);
        int4 s0 = sv[t * 2], s1 = sv[t * 2 + 1];
        int4 d0 = dv[t * 2], d1 = dv[t * 2 + 1];
        float v0 = s[s0.x], v1 = s[s0.y], v2 = s[s0.z], v3 = s[s0.w];
        float v4 = s[s1.x], v5 = s[s1.y], v6 = s[s1.z], v7 = s[s1.w];
        __hip_atomic_fetch_add(&my[d0.x], v0, __ATOMIC_RELAXED, __HIP_MEMORY_SCOPE_WORKGROUP);
        __hip_atomic_fetch_add(&my[d0.y], v1, __ATOMIC_RELAXED, __HIP_MEMORY_SCOPE_WORKGROUP);
        __hip_atomic_fetch_add(&my[d0.z], v2, __ATOMIC_RELAXED, __HIP_MEMORY_SCOPE_WORKGROUP);
        __hip_atomic_fetch_add(&my[d0.w], v3, __ATOMIC_RELAXED, __HIP_MEMORY_SCOPE_WORKGROUP);
        __hip_atomic_fetch_add(&my[d1.x], v4, __ATOMIC_RELAXED, __HIP_MEMORY_SCOPE_WORKGROUP);
        __hip_atomic_fetch_add(&my[d1.y], v5, __ATOMIC_RELAXED, __HIP_MEMORY_SCOPE_WORKGROUP);
        __hip_atomic_fetch_add(&my[d1.z], v6, __ATOMIC_RELAXED, __HIP_MEMORY_SCOPE_WORKGROUP);
        __hip_atomic_fetch_add(&my[d1.w], v7, __ATOMIC_RELAXED, __HIP_MEMORY_SCOPE_WORKGROUP);
    } else {
        for (int k = base; k < E; ++k) {
            int src = ei[k];
            int dst = ei[E + k];
            __hip_atomic_fetch_add(&my[dst], s[src], __ATOMIC_RELAXED, __HIP_MEMORY_SCOPE_WORKGROUP);
        }
    }
}

// out[i] += sum over the 8 per-XCD partials. float4-vectorized.
__global__ void reduce_kernel(const float4* __restrict__ part4,
                              float4* __restrict__ out4,
                              int n4) {
    int i = blockIdx.x * blockDim.x + threadIdx.x;
    if (i >= n4) return;
    float4 a = out4[i];
    #pragma unroll
    for (int k = 0; k < NXCD; ++k) {
        float4 p = part4[k * n4 + i];
        a.x += p.x; a.y += p.y; a.z += p.z; a.w += p.w;
    }
    out4[i] = a;
}

extern "C" void kernel_launch(void* const* d_in, const int* in_sizes, int n_in,
                              void* d_out, int out_size, void* d_ws, size_t ws_size,
                              hipStream_t stream) {
    const float* x      = (const float*)d_in[0];
    const int*   ei     = (const int*)d_in[1];
    const float* W_rel  = (const float*)d_in[2];
    const float* b_rel  = (const float*)d_in[3];
    const float* W_root = (const float*)d_in[4];
    float* out = (float*)d_out;

    int n = out_size;                 // N_NODES (out is [N,1]); divisible by 4
    int E = in_sizes[1] / 2;          // edge_index is [2, E]

    float* part = (float*)d_ws;             // NXCD * n floats of partials
    float* s    = part + (size_t)NXCD * n;  // n floats of rel-scores

    // 1) zero the partials
    int n4p = NXCD * n / 4;
    zero_ws_kernel<<<(n4p + 255) / 256, 256, 0, stream>>>((float4*)part, n4p);

    // 2) per-node scores (16 nodes per block)
    node_scores_kernel<<<(n + 15) / 16, 256, 0, stream>>>(
        (const float4*)x, (const float4*)W_rel, b_rel, (const float4*)W_root,
        s, out, n);

    // 3) edge scatter, 8 edges/thread
    int threads = (E + 7) / 8;
    edge_scatter_kernel<<<(threads + 255) / 256, 256, 0, stream>>>(ei, s, part, E, n);

    // 4) reduce partials into out
    int n4 = n / 4;
    reduce_kernel<<<(n4 + 255) / 256, 256, 0, stream>>>(
        (const float4*)part, (float4*)out, n4);
}

// Round 3
// 45.506 us; speedup vs baseline: 1.8604x; 1.7921x over previous
//
#include <hip/hip_runtime.h>

#define DIM 64
#define RANGES 4

// Kernel 1: 16 threads per node row, float4 loads.
// s[i]   = dot(x[i], W_rel)
// out[i] = dot(x[i], W_root) + b_rel   (full overwrite -> replay-safe)
__global__ void node_scores_kernel(const float4* __restrict__ x4,
                                   const float4* __restrict__ Wrel4,
                                   const float* __restrict__ b_rel,
                                   const float4* __restrict__ Wroot4,
                                   float* __restrict__ s,
                                   float* __restrict__ out,
                                   int n) {
    int tid = threadIdx.x;
    int node = blockIdx.x * 16 + (tid >> 4);
    int c = tid & 15;
    if (node >= n) return;

    float4 xv = x4[(size_t)node * (DIM / 4) + c];
    float4 wr = Wrel4[c];
    float4 wt = Wroot4[c];
    float sr = xv.x * wr.x + xv.y * wr.y + xv.z * wr.z + xv.w * wr.w;
    float st = xv.x * wt.x + xv.y * wt.y + xv.z * wt.z + xv.w * wt.w;

    #pragma unroll
    for (int off = 1; off < 16; off <<= 1) {
        sr += __shfl_xor(sr, off);
        st += __shfl_xor(st, off);
    }
    if (c == 0) {
        s[node]   = sr;
        out[node] = st + b_rel[0];
    }
}

// Kernel 2: LDS-privatized range scatter.
// Grid = RANGES * C. Block (r,c): accumulate edges of chunk c whose dst is in
// range r into a 25K-float LDS accumulator, then store the full slice to
// part[c] (plain stores, full overwrite -> no pre-zero needed).
__global__ void edge_scatter_kernel(const int* __restrict__ ei,
                                    const float* __restrict__ s,
                                    float* __restrict__ part,
                                    int E, int n, int C, int chunk, int range) {
    extern __shared__ float lds[];
    int r = blockIdx.x / C;
    int c = blockIdx.x % C;
    int tid = threadIdx.x;
    int nthr = blockDim.x;

    int base = r * range;
    int rsz = min(range, n - base);          // nodes in this range

    // zero LDS accumulator
    float4* lds4 = (float4*)lds;
    int rsz4 = (rsz + 3) / 4;
    for (int i = tid; i < rsz4; i += nthr) lds4[i] = make_float4(0.f, 0.f, 0.f, 0.f);
    __syncthreads();

    // scan chunk c: edges [c*chunk, min(E,(c+1)*chunk)), chunk % 4 == 0
    int e0 = c * chunk;
    int e1 = min(E, e0 + chunk);
    if (e0 < e1) {
        const int4* sv = (const int4*)ei;          // src row
        const int4* dv = (const int4*)(ei + E);    // dst row
        int g0 = e0 >> 2;
        int g1 = e1 >> 2;                          // E % 4 tail handled below
        for (int g = g0 + tid; g < g1; g += nthr) {
            int4 sg = sv[g];
            int4 dg = dv[g];
            unsigned i0 = (unsigned)(dg.x - base);
            unsigned i1 = (unsigned)(dg.y - base);
            unsigned i2 = (unsigned)(dg.z - base);
            unsigned i3 = (unsigned)(dg.w - base);
            if (i0 < (unsigned)rsz) atomicAdd(&lds[i0], s[sg.x]);
            if (i1 < (unsigned)rsz) atomicAdd(&lds[i1], s[sg.y]);
            if (i2 < (unsigned)rsz) atomicAdd(&lds[i2], s[sg.z]);
            if (i3 < (unsigned)rsz) atomicAdd(&lds[i3], s[sg.w]);
        }
        // scalar tail (E % 4 != 0), only last chunk
        if (tid == 0 && e1 == E) {
            for (int e = (E >> 2) << 2; e < E; ++e) {
                unsigned idx = (unsigned)(ei[E + e] - base);
                if (idx < (unsigned)rsz) atomicAdd(&lds[idx], s[ei[e]]);
            }
        }
    }
    __syncthreads();

    // flush full slice to part[c] (plain stores)
    float* dst = part + (size_t)c * n + base;
    // rsz is a multiple of 4 when n % (4*RANGES) == 0 (100000/4/4=6250 ok)
    if ((rsz & 3) == 0 && ((base & 3) == 0)) {
        float4* d4 = (float4*)dst;
        for (int i = tid; i < (rsz >> 2); i += nthr) d4[i] = lds4[i];
    } else {
        for (int i = tid; i < rsz; i += nthr) dst[i] = lds[i];
    }
}

// Kernel 3: out[i] += sum over C partial copies.
__global__ void reduce_kernel(const float4* __restrict__ part4,
                              float4* __restrict__ out4,
                              int n4, int C) {
    int i = blockIdx.x * blockDim.x + threadIdx.x;
    if (i >= n4) return;
    float4 a = out4[i];
    for (int k = 0; k < C; ++k) {
        float4 p = part4[(size_t)k * n4 + i];
        a.x += p.x; a.y += p.y; a.z += p.z; a.w += p.w;
    }
    out4[i] = a;
}

extern "C" void kernel_launch(void* const* d_in, const int* in_sizes, int n_in,
                              void* d_out, int out_size, void* d_ws, size_t ws_size,
                              hipStream_t stream) {
    const float* x      = (const float*)d_in[0];
    const int*   ei     = (const int*)d_in[1];
    const float* W_rel  = (const float*)d_in[2];
    const float* b_rel  = (const float*)d_in[3];
    const float* W_root = (const float*)d_in[4];
    float* out = (float*)d_out;

    int n = out_size;                 // N_NODES; 100000 (div by 4)
    int E = in_sizes[1] / 2;          // edge_index is [2, E]

    // Adaptive chunk count: need (C+1) * n floats of ws.
    int C = (int)(ws_size / (4 * (size_t)n)) - 1;
    if (C > 64) C = 64;
    if (C < 1)  C = 1;

    float* part = (float*)d_ws;              // C * n floats
    float* s    = part + (size_t)C * n;      // n floats

    // 1) per-node scores
    node_scores_kernel<<<(n + 15) / 16, 256, 0, stream>>>(
        (const float4*)x, (const float4*)W_rel, b_rel, (const float4*)W_root,
        s, out, n);

    // 2) LDS range scatter
    int range = (n + RANGES - 1) / RANGES;           // 25000
    int chunk = ((E + C - 1) / C + 3) & ~3;          // per-chunk edges, %4==0
    size_t lds_bytes = (size_t)range * sizeof(float); // 100000 B
    edge_scatter_kernel<<<RANGES * C, 512, lds_bytes, stream>>>(
        ei, s, part, E, n, C, chunk, range);

    // 3) reduce partials into out
    int n4 = n / 4;
    reduce_kernel<<<(n4 + 255) / 256, 256, 0, stream>>>(
        (const float4*)part, (float4*)out, n4, C);
}